// Round 1
// baseline (50958.362 us; speedup 1.0000x reference)
//
#include <hip/hip_runtime.h>

// LSTM-CRF on MI355X.
// Pipeline: embed -> gemm(gin L0) -> lstm L0 -> gemm(gin L1) -> lstm L1 -> feats -> viterbi.
// Recurrence: 16 persistent WGs (8 per direction), h exchanged per step via tagged
// u64 {version:u32, h:f32} mailbox with agent-scope relaxed atomics.

#define T_SEQ 4096
#define HPAD  512
#define NTAG  16

// ---------------- workspace layout (bytes) ----------------
// x0   : [4096][512]  f32   8388608  @ 0
// x1   : [4096][1024] f32  16777216  @ 8388608
// x2   : [4096][1024] f32  16777216  @ 25165824
// gin  : [2][4096][2048] f32 67108864 @ 41943040
// feats: [4096][16] f32     262144  @ 109051904
// bptr : [4096][16] i32     262144  @ 109314048
// hcomm: [2][2][512] u64     16384  @ 109576192
// total ~104.5 MB

__global__ void zero_k(float* __restrict__ p, int n) {
  int i = blockIdx.x * blockDim.x + threadIdx.x;
  int stride = gridDim.x * blockDim.x;
  for (; i < n; i += stride) p[i] = 0.0f;
}

__global__ void embed_k(const int* __restrict__ sent, const float* __restrict__ ew,
                        float* __restrict__ x0) {
  int t = blockIdx.x;
  int row = sent[t];
  for (int k = threadIdx.x; k < HPAD; k += blockDim.x)
    x0[(size_t)t * HPAD + k] = (k < 500) ? ew[(size_t)row * 500 + k] : 0.0f;
}

// G[dir][t][n] = sum_k A[t][k] * Wmap[dir][n][k] + bias[n]  (f32, 128x128 tile, 8x8/thread)
__global__ __launch_bounds__(256) void gin_gemm_k(
    const float* __restrict__ A, int KA,
    const float* __restrict__ wih, const float* __restrict__ bih,
    const float* __restrict__ bhh, int Kreal, float* __restrict__ G) {
  const int dir = blockIdx.z;
  const int bm = blockIdx.y, bn = blockIdx.x;
  const float* W = wih + (size_t)dir * 2000 * Kreal;

  __shared__ float As[16][128];
  __shared__ float Bs[16][128];

  const int tid = threadIdx.x;
  const int tx = tid & 15, ty = tid >> 4;
  float acc[8][8] = {};

  for (int k0 = 0; k0 < KA; k0 += 16) {
#pragma unroll
    for (int q = 0; q < 2; q++) {
      int f4 = tid + q * 256;              // 0..511
      int m = f4 >> 2, kc = (f4 & 3) * 4;
      float4 av = *reinterpret_cast<const float4*>(A + (size_t)(bm * 128 + m) * KA + k0 + kc);
      As[kc + 0][m] = av.x; As[kc + 1][m] = av.y;
      As[kc + 2][m] = av.z; As[kc + 3][m] = av.w;
    }
#pragma unroll
    for (int q = 0; q < 2; q++) {
      int f4 = tid + q * 256;
      int n = f4 >> 2, kc = (f4 & 3) * 4;
      int nn = bn * 128 + n;
      int gate = nn >> 9, j = nn & 511;
#pragma unroll
      for (int e = 0; e < 4; e++) {
        int k = k0 + kc + e;
        int jk = k & 511, half = k >> 9;
        float v = 0.0f;
        if (j < 500 && jk < 500)
          v = W[(size_t)(gate * 500 + j) * Kreal + half * 500 + jk];
        Bs[kc + e][n] = v;
      }
    }
    __syncthreads();
#pragma unroll
    for (int kk = 0; kk < 16; kk++) {
      float a[8], b[8];
      *reinterpret_cast<float4*>(&a[0]) = *reinterpret_cast<const float4*>(&As[kk][ty * 8]);
      *reinterpret_cast<float4*>(&a[4]) = *reinterpret_cast<const float4*>(&As[kk][ty * 8 + 4]);
      *reinterpret_cast<float4*>(&b[0]) = *reinterpret_cast<const float4*>(&Bs[kk][tx * 8]);
      *reinterpret_cast<float4*>(&b[4]) = *reinterpret_cast<const float4*>(&Bs[kk][tx * 8 + 4]);
#pragma unroll
      for (int i = 0; i < 8; i++)
#pragma unroll
        for (int j = 0; j < 8; j++) acc[i][j] = fmaf(a[i], b[j], acc[i][j]);
    }
    __syncthreads();
  }
#pragma unroll
  for (int i = 0; i < 8; i++) {
#pragma unroll
    for (int j = 0; j < 8; j++) {
      int m = bm * 128 + ty * 8 + i;
      int nn = bn * 128 + tx * 8 + j;
      int gate = nn >> 9, ju = nn & 511;
      float o = 0.0f;
      if (ju < 500) {
        int r = gate * 500 + ju;
        o = acc[i][j] + bih[dir * 2000 + r] + bhh[dir * 2000 + r];
      }
      G[((size_t)dir * T_SEQ + m) * 2048 + nn] = o;
    }
  }
}

__device__ __forceinline__ unsigned long long pack_hv(unsigned tag, float h) {
  return (unsigned long long)tag | ((unsigned long long)__float_as_uint(h) << 32);
}

__global__ void hinit_k(const float* __restrict__ h0, int layer,
                        unsigned long long* __restrict__ hcomm) {
  int i = blockIdx.x * blockDim.x + threadIdx.x;   // 0..2047
  int dir = i >> 10, par = (i >> 9) & 1, j = i & 511;
  unsigned long long v;
  if (par == 0) {
    float h = (j < 500) ? h0[(layer * 2 + dir) * 500 + j] : 0.0f;
    v = pack_hv(0u, h);
  } else {
    v = 0xFFFFFFFFull;   // sentinel tag, value 0
  }
  hcomm[(size_t)(dir * 2 + par) * HPAD + j] = v;
}

// Persistent recurrence kernel: 16 WGs x 1024 threads.  WG = (dir, wgd); owns 64 units.
// Wave w owns k-slice [w*32, w*32+32); lane owns 4 rows (gate=lane>>4, units (lane&15)*4+s).
__global__ __launch_bounds__(1024, 4) void lstm_k(
    const float* __restrict__ whh_base,   // [2][2000][500]
    const float* __restrict__ gin,        // [2][4096][2048]
    const float* __restrict__ c0,         // [4][500]
    float* __restrict__ xout,             // [4096][1024]
    unsigned long long* __restrict__ hcomm, // [2][2][512]
    int layer) {
  const int wg = blockIdx.x;
  const int dir = wg >> 3;
  const int wgd = wg & 7;
  const int tid = threadIdx.x;
  const int w = tid >> 6;
  const int lane = tid & 63;

  __shared__ float part[16][256];

  // ---- load recurrent weights into registers ----
  const int lg = lane >> 4;           // my rows' gate
  const int lj = (lane & 15) * 4;     // my rows' local-unit base
  float wreg[4][32];
  const float* Wd = whh_base + (size_t)dir * 2000 * 500;
#pragma unroll
  for (int s = 0; s < 4; s++) {
    int j = wgd * 64 + lj + s;
    int row = lg * 500 + j;
#pragma unroll
    for (int i = 0; i < 32; i++) {
      int k = w * 32 + i;
      wreg[s][i] = (j < 500 && k < 500) ? Wd[(size_t)row * 500 + k] : 0.0f;
    }
  }

  // wave0: persistent cell state (one unit per lane)
  float c = 0.0f;
  const int jmine = wgd * 64 + lane;
  if (w == 0 && jmine < 500) c = c0[(layer * 2 + dir) * 500 + jmine];

  unsigned long long* hcd = hcomm + (size_t)dir * 2 * HPAD;

  for (int t = 0; t < T_SEQ; t++) {
    const int t_in = (dir == 0) ? t : (T_SEQ - 1 - t);

    // prefetch input-projection gates (latency hidden under poll)
    float gi0 = 0, gi1 = 0, gi2 = 0, gi3 = 0;
    if (w == 0) {
      const float* gb = gin + ((size_t)dir * T_SEQ + t_in) * 2048;
      gi0 = gb[jmine];
      gi1 = gb[512 + jmine];
      gi2 = gb[1024 + jmine];
      gi3 = gb[1536 + jmine];
    }

    // ---- poll my wave's h k-slice (tag==t) ----
    unsigned long long v;
    {
      const unsigned long long* hp =
          hcd + (size_t)(t & 1) * HPAD + w * 32 + (lane & 31);
      int guard = 0;
      for (;;) {
        v = __hip_atomic_load(hp, __ATOMIC_RELAXED, __HIP_MEMORY_SCOPE_AGENT);
        if (__all((int)((unsigned)v == (unsigned)t))) break;
        if (++guard > (1 << 24)) break;   // anti-hang bail (never in correct runs)
      }
    }
    float hval = __uint_as_float((unsigned)(v >> 32));

    // ---- matvec partials over my 32-k slice ----
    float a0 = 0, a1 = 0, a2 = 0, a3 = 0;
#pragma unroll
    for (int i = 0; i < 32; i++) {
      float hv = __shfl(hval, i, 32);
      a0 = fmaf(wreg[0][i], hv, a0);
      a1 = fmaf(wreg[1][i], hv, a1);
      a2 = fmaf(wreg[2][i], hv, a2);
      a3 = fmaf(wreg[3][i], hv, a3);
    }
    {
      float4 pv;
      pv.x = a0; pv.y = a1; pv.z = a2; pv.w = a3;
      *reinterpret_cast<float4*>(&part[w][lane * 4]) = pv;   // rr = lane*4+s = gate*64+unit
    }
    __syncthreads();

    // ---- cross-wave reduce: 4 threads per row over 16 wave-partials ----
    {
      int rr = tid >> 2, q = tid & 3;
      float sum = part[q * 4 + 0][rr] + part[q * 4 + 1][rr] +
                  part[q * 4 + 2][rr] + part[q * 4 + 3][rr];
      sum += __shfl_xor(sum, 1, 4);
      sum += __shfl_xor(sum, 2, 4);
      if (q == 0) part[0][rr] = sum;
    }
    __syncthreads();

    // ---- wave0: gate nonlinearity, state update, publish h ----
    if (w == 0) {
      float xi = 1.0f / (1.0f + expf(-(part[0][lane] + gi0)));
      float xf = 1.0f / (1.0f + expf(-(part[0][64 + lane] + gi1)));
      float xg = tanhf(part[0][128 + lane] + gi2);
      float xo = 1.0f / (1.0f + expf(-(part[0][192 + lane] + gi3)));
      c = xf * c + xi * xg;
      float h = xo * tanhf(c);
      if (jmine < 500)
        xout[(size_t)t_in * 1024 + (size_t)dir * HPAD + jmine] = h;
      unsigned long long sv = pack_hv((unsigned)(t + 1), h);
      __hip_atomic_store(hcd + (size_t)((t + 1) & 1) * HPAD + jmine, sv,
                         __ATOMIC_RELAXED, __HIP_MEMORY_SCOPE_AGENT);
    }
  }
}

// feats[t][tag] = sum_k x2[t][k]*w_out[tag][k_real] + b_out[tag]
__global__ __launch_bounds__(256) void feats_k(
    const float* __restrict__ x2, const float* __restrict__ w_out,
    const float* __restrict__ b_out, float* __restrict__ feats) {
  int tid = threadIdx.x;
  int tag = tid & 15, tl = tid >> 4;
  int t = blockIdx.x * 16 + tl;
  float acc = 0.0f;
  for (int k = 0; k < 1024; k++) {
    int jk = k & 511;
    if (jk < 500)
      acc = fmaf(x2[(size_t)t * 1024 + k], w_out[tag * 1000 + (k >> 9) * 500 + jk], acc);
  }
  feats[t * 16 + tag] = acc + b_out[tag];
}

__global__ __launch_bounds__(256) void viterbi_k(
    const float* __restrict__ feats, const float* __restrict__ trans,
    int* __restrict__ bptr, float* __restrict__ out) {
  __shared__ float sfin[NTAG];
  __shared__ int sbest;
  int tid = threadIdx.x;
  if (tid < 64) {
    int tag = tid & 15;
    float treg[16];
#pragma unroll
    for (int p = 0; p < 16; p++) treg[p] = trans[tag * 16 + p];
    float s = (tag == 14) ? 0.0f : -10000.0f;   // START=14
    for (int t = 0; t < T_SEQ; t++) {
      float best = -3.4e38f;
      int barg = 0;
#pragma unroll
      for (int p = 0; p < 16; p++) {
        float cand = __shfl(s, p, 16) + treg[p];
        if (cand > best) { best = cand; barg = p; }   // strict > : first-max (np.argmax)
      }
      s = best + feats[t * 16 + tag];
      if (tid < 16) bptr[t * 16 + tag] = barg;
    }
    s += trans[15 * 16 + tag];                   // STOP=15
    if (tid < 16) sfin[tag] = s;
  }
  __syncthreads();
  if (tid == 0) {
    float best = -3.4e38f;
    int bt = 0;
    for (int p = 0; p < 16; p++) {
      float vv = sfin[p];
      if (vv > best) { best = vv; bt = p; }
    }
    out[0] = best;
    sbest = bt;
  }
  __syncthreads();
  int bt = sbest;
  for (int i = tid; i < T_SEQ - 1; i += blockDim.x)
    out[1 + i] = (float)bptr[(i + 1) * 16 + bt];
  if (tid == 0) out[T_SEQ] = (float)bt;
}

extern "C" void kernel_launch(void* const* d_in, const int* in_sizes, int n_in,
                              void* d_out, int out_size, void* d_ws, size_t ws_size,
                              hipStream_t stream) {
  const int*   sent  = (const int*)d_in[0];
  const float* embed = (const float*)d_in[1];
  const float* wih0  = (const float*)d_in[2];
  const float* whh0  = (const float*)d_in[3];
  const float* bih0  = (const float*)d_in[4];
  const float* bhh0  = (const float*)d_in[5];
  const float* wih1  = (const float*)d_in[6];
  const float* whh1  = (const float*)d_in[7];
  const float* bih1  = (const float*)d_in[8];
  const float* bhh1  = (const float*)d_in[9];
  const float* w_out = (const float*)d_in[10];
  const float* b_out = (const float*)d_in[11];
  const float* trans = (const float*)d_in[12];
  const float* h0    = (const float*)d_in[13];
  const float* c0    = (const float*)d_in[14];
  float* out = (float*)d_out;

  char* ws = (char*)d_ws;
  float* x0    = (float*)(ws + 0);
  float* x1    = (float*)(ws + 8388608);
  float* x2    = (float*)(ws + 25165824);
  float* gin   = (float*)(ws + 41943040);
  float* feats = (float*)(ws + 109051904);
  int*   bptr  = (int*)(ws + 109314048);
  unsigned long long* hcomm = (unsigned long long*)(ws + 109576192);

  // zero x1+x2 (contiguous 32MB) so pad columns are 0
  zero_k<<<2048, 256, 0, stream>>>(x1, 2 * T_SEQ * 1024);
  embed_k<<<T_SEQ, 256, 0, stream>>>(sent, embed, x0);

  // layer 0
  gin_gemm_k<<<dim3(16, 32, 2), 256, 0, stream>>>(x0, 512, wih0, bih0, bhh0, 500, gin);
  hinit_k<<<2, 1024, 0, stream>>>(h0, 0, hcomm);
  lstm_k<<<16, 1024, 0, stream>>>(whh0, gin, c0, x1, hcomm, 0);

  // layer 1
  gin_gemm_k<<<dim3(16, 32, 2), 256, 0, stream>>>(x1, 1024, wih1, bih1, bhh1, 1000, gin);
  hinit_k<<<2, 1024, 0, stream>>>(h0, 1, hcomm);
  lstm_k<<<16, 1024, 0, stream>>>(whh1, gin, c0, x2, hcomm, 1);

  // output projection + viterbi
  feats_k<<<T_SEQ / 16, 256, 0, stream>>>(x2, w_out, b_out, feats);
  viterbi_k<<<1, 256, 0, stream>>>(feats, trans, bptr, out);
}

// Round 4
// 26997.250 us; speedup vs baseline: 1.8875x; 1.8875x over previous
//
#include <hip/hip_runtime.h>

// LSTM-CRF on MI355X.
// Pipeline: embed -> gemm(gin L0) -> lstm L0 -> gemm(gin L1) -> lstm L1 -> feats -> viterbi.
// Recurrence: 16 WGs per direction (32 units each), h exchanged per step via tagged u64
// {tag:u32, h:f32} mailbox with DEVICE-SCOPE relaxed atomics (round-1-proven semantics;
// the round-2/3 XCD-local L2 scheme corrupted deterministically and is abandoned).
// Round-1's hidden perf bug fixed here: __launch_bounds__(1024,4) had capped VGPR at 64,
// spilling the weight registers to scratch (~10K cy/step). Now wreg[2][32] (~100 VGPR)
// fits the 128-VGPR cap of __launch_bounds__(1024) -> no spill.

#define T_SEQ 4096
#define HPAD  512
#define NTAG  16

// ---------------- workspace layout (bytes) ----------------
// x0   : [4096][512]  f32   8388608  @ 0
// x1   : [4096][1024] f32  16777216  @ 8388608
// x2   : [4096][1024] f32  16777216  @ 25165824
// gin  : [2][4096][2048] f32 67108864 @ 41943040
// feats: [4096][16] f32     262144  @ 109051904
// bptr : [4096][16] i32     262144  @ 109314048
// hcomm: [2][2][512] u64     16384  @ 109576192

__global__ void zero_k(float* __restrict__ p, int n) {
  int i = blockIdx.x * blockDim.x + threadIdx.x;
  int stride = gridDim.x * blockDim.x;
  for (; i < n; i += stride) p[i] = 0.0f;
}

__global__ void embed_k(const int* __restrict__ sent, const float* __restrict__ ew,
                        float* __restrict__ x0) {
  int t = blockIdx.x;
  int row = sent[t];
  for (int k = threadIdx.x; k < HPAD; k += blockDim.x)
    x0[(size_t)t * HPAD + k] = (k < 500) ? ew[(size_t)row * 500 + k] : 0.0f;
}

// G[dir][t][n] = sum_k A[t][k] * Wmap[dir][n][k] + bias[n]  (f32, 128x128 tile, 8x8/thread)
__global__ __launch_bounds__(256) void gin_gemm_k(
    const float* __restrict__ A, int KA,
    const float* __restrict__ wih, const float* __restrict__ bih,
    const float* __restrict__ bhh, int Kreal, float* __restrict__ G) {
  const int dir = blockIdx.z;
  const int bm = blockIdx.y, bn = blockIdx.x;
  const float* W = wih + (size_t)dir * 2000 * Kreal;

  __shared__ float As[16][128];
  __shared__ float Bs[16][128];

  const int tid = threadIdx.x;
  const int tx = tid & 15, ty = tid >> 4;
  float acc[8][8] = {};

  for (int k0 = 0; k0 < KA; k0 += 16) {
#pragma unroll
    for (int q = 0; q < 2; q++) {
      int f4 = tid + q * 256;              // 0..511
      int m = f4 >> 2, kc = (f4 & 3) * 4;
      float4 av = *reinterpret_cast<const float4*>(A + (size_t)(bm * 128 + m) * KA + k0 + kc);
      As[kc + 0][m] = av.x; As[kc + 1][m] = av.y;
      As[kc + 2][m] = av.z; As[kc + 3][m] = av.w;
    }
#pragma unroll
    for (int q = 0; q < 2; q++) {
      int f4 = tid + q * 256;
      int n = f4 >> 2, kc = (f4 & 3) * 4;
      int nn = bn * 128 + n;
      int gate = nn >> 9, j = nn & 511;
#pragma unroll
      for (int e = 0; e < 4; e++) {
        int k = k0 + kc + e;
        int jk = k & 511, half = k >> 9;
        float v = 0.0f;
        if (j < 500 && jk < 500)
          v = W[(size_t)(gate * 500 + j) * Kreal + half * 500 + jk];
        Bs[kc + e][n] = v;
      }
    }
    __syncthreads();
#pragma unroll
    for (int kk = 0; kk < 16; kk++) {
      float a[8], b[8];
      *reinterpret_cast<float4*>(&a[0]) = *reinterpret_cast<const float4*>(&As[kk][ty * 8]);
      *reinterpret_cast<float4*>(&a[4]) = *reinterpret_cast<const float4*>(&As[kk][ty * 8 + 4]);
      *reinterpret_cast<float4*>(&b[0]) = *reinterpret_cast<const float4*>(&Bs[kk][tx * 8]);
      *reinterpret_cast<float4*>(&b[4]) = *reinterpret_cast<const float4*>(&Bs[kk][tx * 8 + 4]);
#pragma unroll
      for (int i = 0; i < 8; i++)
#pragma unroll
        for (int j = 0; j < 8; j++) acc[i][j] = fmaf(a[i], b[j], acc[i][j]);
    }
    __syncthreads();
  }
#pragma unroll
  for (int i = 0; i < 8; i++) {
#pragma unroll
    for (int j = 0; j < 8; j++) {
      int m = bm * 128 + ty * 8 + i;
      int nn = bn * 128 + tx * 8 + j;
      int gate = nn >> 9, ju = nn & 511;
      float o = 0.0f;
      if (ju < 500) {
        int r = gate * 500 + ju;
        o = acc[i][j] + bih[dir * 2000 + r] + bhh[dir * 2000 + r];
      }
      G[((size_t)dir * T_SEQ + m) * 2048 + nn] = o;
    }
  }
}

__device__ __forceinline__ unsigned long long pack_hv(unsigned tag, float h) {
  return (unsigned long long)tag | ((unsigned long long)__float_as_uint(h) << 32);
}

__global__ void hinit_k(const float* __restrict__ h0, int layer,
                        unsigned long long* __restrict__ hcomm) {
  int i = blockIdx.x * blockDim.x + threadIdx.x;   // 0..2047
  int dir = i >> 10, par = (i >> 9) & 1, j = i & 511;
  unsigned long long v;
  if (par == 0) {
    float h = (j < 500) ? h0[(layer * 2 + dir) * 500 + j] : 0.0f;
    v = pack_hv(0u, h);
  } else {
    v = 0xFFFFFFFFull;   // sentinel tag, value 0
  }
  hcomm[(size_t)(dir * 2 + par) * HPAD + j] = v;
}

// Persistent recurrence kernel: 32 WGs x 1024 threads; WG = (dir = blockIdx>>4,
// wgd = blockIdx&15) owns units [wgd*32, wgd*32+32).
// Wave w owns k-slice [w*32, w*32+32); lane owns 2 rows (r = lane*2+s,
// gate = r>>5, unit = r&31) -> wreg[2][32], ~100 VGPR, no spill.
__global__ __launch_bounds__(1024) void lstm_k(
    const float* __restrict__ whh_base,   // [2][2000][500]
    const float* __restrict__ gin,        // [2][4096][2048]
    const float* __restrict__ c0,         // [4][500]
    float* __restrict__ xout,             // [4096][1024]
    unsigned long long* __restrict__ hcomm, // [2][2][512]
    int layer) {
  __shared__ float part[16][128];

  const int tid = threadIdx.x;
  const int dir = blockIdx.x >> 4;
  const int wgd = blockIdx.x & 15;              // unit block [wgd*32, wgd*32+32)
  const int w = tid >> 6;
  const int lane = tid & 63;

  // ---- load recurrent weights into registers (2 rows x 32 k per lane) ----
  float wreg[2][32];
  const float* Wd = whh_base + (size_t)dir * 2000 * 500;
#pragma unroll
  for (int s = 0; s < 2; s++) {
    int rloc = lane * 2 + s;                    // 0..127
    int gate = rloc >> 5, u = rloc & 31;
    int j = wgd * 32 + u;
    int row = gate * 500 + j;
#pragma unroll
    for (int i = 0; i < 32; i++) {
      int k = w * 32 + i;
      wreg[s][i] = (j < 500 && k < 500) ? Wd[(size_t)row * 500 + k] : 0.0f;
    }
  }

  // wave0 lanes<32: persistent cell state (one unit per lane)
  float c = 0.0f;
  const int jmine = wgd * 32 + (lane & 31);
  if (w == 0 && lane < 32 && jmine < 500) c = c0[(layer * 2 + dir) * 500 + jmine];

  unsigned long long* hcd = hcomm + (size_t)dir * 2 * HPAD;
  bool dead = false;

  for (int t = 0; t < T_SEQ; t++) {
    const int t_in = (dir == 0) ? t : (T_SEQ - 1 - t);

    // prefetch input-projection gates (latency hidden under poll)
    float gi0 = 0, gi1 = 0, gi2 = 0, gi3 = 0;
    if (w == 0 && lane < 32) {
      const float* gb = gin + ((size_t)dir * T_SEQ + t_in) * 2048;
      gi0 = gb[jmine];
      gi1 = gb[512 + jmine];
      gi2 = gb[1024 + jmine];
      gi3 = gb[1536 + jmine];
    }

    // ---- poll my wave's h k-slice (tag==t), device-scope (round-1-proven) ----
    unsigned long long v = 0;
    if (!dead) {
      const unsigned long long* hp =
          hcd + (size_t)(t & 1) * HPAD + w * 32 + (lane & 31);
      int guard = 0;
      for (;;) {
        v = __hip_atomic_load(hp, __ATOMIC_RELAXED, __HIP_MEMORY_SCOPE_AGENT);
        if (__all((int)((unsigned)v == (unsigned)t))) break;
        if (++guard > (1 << 22)) { dead = true; break; }   // bail, never hang
      }
    }
    float hval = __uint_as_float((unsigned)(v >> 32));

    // ---- matvec partials over my 32-k slice (2 rows/lane) ----
    float a0 = 0, a1 = 0;
#pragma unroll
    for (int i = 0; i < 32; i++) {
      float hv = __shfl(hval, i, 32);
      a0 = fmaf(wreg[0][i], hv, a0);
      a1 = fmaf(wreg[1][i], hv, a1);
    }
    {
      float2 pv; pv.x = a0; pv.y = a1;
      *reinterpret_cast<float2*>(&part[w][lane * 2]) = pv;  // row r = lane*2+s
    }
    __syncthreads();

    // ---- cross-wave reduce: 8 threads per row over 16 wave-partials ----
    {
      int rr = tid >> 3, q = tid & 7;           // rr 0..127
      float sum = part[q][rr] + part[q + 8][rr];
      sum += __shfl_xor(sum, 1, 8);
      sum += __shfl_xor(sum, 2, 8);
      sum += __shfl_xor(sum, 4, 8);
      if (q == 0) part[0][rr] = sum;
    }
    __syncthreads();

    // ---- wave0 lanes<32: gate nonlinearity, state update, publish h ----
    if (w == 0 && lane < 32) {
      float xi = 1.0f / (1.0f + expf(-(part[0][lane] + gi0)));
      float xf = 1.0f / (1.0f + expf(-(part[0][32 + lane] + gi1)));
      float xg = tanhf(part[0][64 + lane] + gi2);
      float xo = 1.0f / (1.0f + expf(-(part[0][96 + lane] + gi3)));
      c = xf * c + xi * xg;
      float h = xo * tanhf(c);
      if (jmine < 500)
        xout[(size_t)t_in * 1024 + (size_t)dir * HPAD + jmine] = h;
      unsigned long long sv = pack_hv((unsigned)(t + 1), h);
      __hip_atomic_store(hcd + (size_t)((t + 1) & 1) * HPAD + jmine, sv,
                         __ATOMIC_RELAXED, __HIP_MEMORY_SCOPE_AGENT);
    }
  }
}

// feats[t][tag] = sum_k x2[t][k]*w_out[tag][k_real] + b_out[tag]
__global__ __launch_bounds__(256) void feats_k(
    const float* __restrict__ x2, const float* __restrict__ w_out,
    const float* __restrict__ b_out, float* __restrict__ feats) {
  int tid = threadIdx.x;
  int tag = tid & 15, tl = tid >> 4;
  int t = blockIdx.x * 16 + tl;
  float acc = 0.0f;
  for (int k = 0; k < 1024; k++) {
    int jk = k & 511;
    if (jk < 500)
      acc = fmaf(x2[(size_t)t * 1024 + k], w_out[tag * 1000 + (k >> 9) * 500 + jk], acc);
  }
  feats[t * 16 + tag] = acc + b_out[tag];
}

__global__ __launch_bounds__(256) void viterbi_k(
    const float* __restrict__ feats, const float* __restrict__ trans,
    int* __restrict__ bptr, float* __restrict__ out) {
  __shared__ float sfin[NTAG];
  __shared__ int sbest;
  int tid = threadIdx.x;
  if (tid < 64) {
    int tag = tid & 15;
    float treg[16];
#pragma unroll
    for (int p = 0; p < 16; p++) treg[p] = trans[tag * 16 + p];
    float s = (tag == 14) ? 0.0f : -10000.0f;   // START=14
    for (int t = 0; t < T_SEQ; t++) {
      float best = -3.4e38f;
      int barg = 0;
#pragma unroll
      for (int p = 0; p < 16; p++) {
        float cand = __shfl(s, p, 16) + treg[p];
        if (cand > best) { best = cand; barg = p; }   // strict > : first-max (np.argmax)
      }
      s = best + feats[t * 16 + tag];
      if (tid < 16) bptr[t * 16 + tag] = barg;
    }
    s += trans[15 * 16 + tag];                   // STOP=15
    if (tid < 16) sfin[tag] = s;
  }
  __syncthreads();
  if (tid == 0) {
    float best = -3.4e38f;
    int bt = 0;
    for (int p = 0; p < 16; p++) {
      float vv = sfin[p];
      if (vv > best) { best = vv; bt = p; }
    }
    out[0] = best;
    sbest = bt;
  }
  __syncthreads();
  int bt = sbest;
  for (int i = tid; i < T_SEQ - 1; i += blockDim.x)
    out[1 + i] = (float)bptr[(i + 1) * 16 + bt];
  if (tid == 0) out[T_SEQ] = (float)bt;
}

extern "C" void kernel_launch(void* const* d_in, const int* in_sizes, int n_in,
                              void* d_out, int out_size, void* d_ws, size_t ws_size,
                              hipStream_t stream) {
  const int*   sent  = (const int*)d_in[0];
  const float* embed = (const float*)d_in[1];
  const float* wih0  = (const float*)d_in[2];
  const float* whh0  = (const float*)d_in[3];
  const float* bih0  = (const float*)d_in[4];
  const float* bhh0  = (const float*)d_in[5];
  const float* wih1  = (const float*)d_in[6];
  const float* whh1  = (const float*)d_in[7];
  const float* bih1  = (const float*)d_in[8];
  const float* bhh1  = (const float*)d_in[9];
  const float* w_out = (const float*)d_in[10];
  const float* b_out = (const float*)d_in[11];
  const float* trans = (const float*)d_in[12];
  const float* h0    = (const float*)d_in[13];
  const float* c0    = (const float*)d_in[14];
  float* out = (float*)d_out;

  char* ws = (char*)d_ws;
  float* x0    = (float*)(ws + 0);
  float* x1    = (float*)(ws + 8388608);
  float* x2    = (float*)(ws + 25165824);
  float* gin   = (float*)(ws + 41943040);
  float* feats = (float*)(ws + 109051904);
  int*   bptr  = (int*)(ws + 109314048);
  unsigned long long* hcomm = (unsigned long long*)(ws + 109576192);

  // zero x1+x2 (contiguous 32MB) so pad columns are 0
  zero_k<<<2048, 256, 0, stream>>>(x1, 2 * T_SEQ * 1024);
  embed_k<<<T_SEQ, 256, 0, stream>>>(sent, embed, x0);

  // layer 0
  gin_gemm_k<<<dim3(16, 32, 2), 256, 0, stream>>>(x0, 512, wih0, bih0, bhh0, 500, gin);
  hinit_k<<<2, 1024, 0, stream>>>(h0, 0, hcomm);
  lstm_k<<<32, 1024, 0, stream>>>(whh0, gin, c0, x1, hcomm, 0);

  // layer 1
  gin_gemm_k<<<dim3(16, 32, 2), 256, 0, stream>>>(x1, 1024, wih1, bih1, bhh1, 1000, gin);
  hinit_k<<<2, 1024, 0, stream>>>(h0, 1, hcomm);
  lstm_k<<<32, 1024, 0, stream>>>(whh1, gin, c0, x2, hcomm, 1);

  // output projection + viterbi
  feats_k<<<T_SEQ / 16, 256, 0, stream>>>(x2, w_out, b_out, feats);
  viterbi_k<<<1, 256, 0, stream>>>(feats, trans, bptr, out);
}

// Round 5
// 19156.589 us; speedup vs baseline: 2.6601x; 1.4093x over previous
//
#include <hip/hip_runtime.h>

// LSTM-CRF on MI355X.
// Pipeline: embed -> gemm(gin L0) -> lstm L0 -> gemm(gin L1) -> lstm L1 -> feats -> viterbi.
// Recurrence: 16 WGs per direction (32 units each), h exchanged per step via tagged u64
// {tag:u32, h:f32} mailbox with DEVICE-SCOPE relaxed atomics (round-1/4-proven semantics).
// Round-4 lesson (from counters): WRITE_SIZE had no scratch component but VGPR_Count=64 ->
// compiler chose 8-waves/EU occupancy and REMATERIALIZED the weight array by re-loading
// whh from L1/L2 every step (~256KB/CU/step through the ~64B/cy L1 port ~ 4100 cy/step).
// Fix: pin amdgpu_waves_per_eu(4,4) (a 16-wave WG needs 4 waves/EU regardless) -> 128-VGPR
// budget -> wreg[2][32] stays register-resident. Also swap the 32-shfl h-broadcast for an
// LDS write + 8x ds_read_b128 (fewer DS ops on the critical path).

#define T_SEQ 4096
#define HPAD  512
#define NTAG  16

// ---------------- workspace layout (bytes) ----------------
// x0   : [4096][512]  f32   8388608  @ 0
// x1   : [4096][1024] f32  16777216  @ 8388608
// x2   : [4096][1024] f32  16777216  @ 25165824
// gin  : [2][4096][2048] f32 67108864 @ 41943040
// feats: [4096][16] f32     262144  @ 109051904
// bptr : [4096][16] i32     262144  @ 109314048
// hcomm: [2][2][512] u64     16384  @ 109576192

__global__ void zero_k(float* __restrict__ p, int n) {
  int i = blockIdx.x * blockDim.x + threadIdx.x;
  int stride = gridDim.x * blockDim.x;
  for (; i < n; i += stride) p[i] = 0.0f;
}

__global__ void embed_k(const int* __restrict__ sent, const float* __restrict__ ew,
                        float* __restrict__ x0) {
  int t = blockIdx.x;
  int row = sent[t];
  for (int k = threadIdx.x; k < HPAD; k += blockDim.x)
    x0[(size_t)t * HPAD + k] = (k < 500) ? ew[(size_t)row * 500 + k] : 0.0f;
}

// G[dir][t][n] = sum_k A[t][k] * Wmap[dir][n][k] + bias[n]  (f32, 128x128 tile, 8x8/thread)
__global__ __launch_bounds__(256) void gin_gemm_k(
    const float* __restrict__ A, int KA,
    const float* __restrict__ wih, const float* __restrict__ bih,
    const float* __restrict__ bhh, int Kreal, float* __restrict__ G) {
  const int dir = blockIdx.z;
  const int bm = blockIdx.y, bn = blockIdx.x;
  const float* W = wih + (size_t)dir * 2000 * Kreal;

  __shared__ float As[16][128];
  __shared__ float Bs[16][128];

  const int tid = threadIdx.x;
  const int tx = tid & 15, ty = tid >> 4;
  float acc[8][8] = {};

  for (int k0 = 0; k0 < KA; k0 += 16) {
#pragma unroll
    for (int q = 0; q < 2; q++) {
      int f4 = tid + q * 256;              // 0..511
      int m = f4 >> 2, kc = (f4 & 3) * 4;
      float4 av = *reinterpret_cast<const float4*>(A + (size_t)(bm * 128 + m) * KA + k0 + kc);
      As[kc + 0][m] = av.x; As[kc + 1][m] = av.y;
      As[kc + 2][m] = av.z; As[kc + 3][m] = av.w;
    }
#pragma unroll
    for (int q = 0; q < 2; q++) {
      int f4 = tid + q * 256;
      int n = f4 >> 2, kc = (f4 & 3) * 4;
      int nn = bn * 128 + n;
      int gate = nn >> 9, j = nn & 511;
#pragma unroll
      for (int e = 0; e < 4; e++) {
        int k = k0 + kc + e;
        int jk = k & 511, half = k >> 9;
        float v = 0.0f;
        if (j < 500 && jk < 500)
          v = W[(size_t)(gate * 500 + j) * Kreal + half * 500 + jk];
        Bs[kc + e][n] = v;
      }
    }
    __syncthreads();
#pragma unroll
    for (int kk = 0; kk < 16; kk++) {
      float a[8], b[8];
      *reinterpret_cast<float4*>(&a[0]) = *reinterpret_cast<const float4*>(&As[kk][ty * 8]);
      *reinterpret_cast<float4*>(&a[4]) = *reinterpret_cast<const float4*>(&As[kk][ty * 8 + 4]);
      *reinterpret_cast<float4*>(&b[0]) = *reinterpret_cast<const float4*>(&Bs[kk][tx * 8]);
      *reinterpret_cast<float4*>(&b[4]) = *reinterpret_cast<const float4*>(&Bs[kk][tx * 8 + 4]);
#pragma unroll
      for (int i = 0; i < 8; i++)
#pragma unroll
        for (int j = 0; j < 8; j++) acc[i][j] = fmaf(a[i], b[j], acc[i][j]);
    }
    __syncthreads();
  }
#pragma unroll
  for (int i = 0; i < 8; i++) {
#pragma unroll
    for (int j = 0; j < 8; j++) {
      int m = bm * 128 + ty * 8 + i;
      int nn = bn * 128 + tx * 8 + j;
      int gate = nn >> 9, ju = nn & 511;
      float o = 0.0f;
      if (ju < 500) {
        int r = gate * 500 + ju;
        o = acc[i][j] + bih[dir * 2000 + r] + bhh[dir * 2000 + r];
      }
      G[((size_t)dir * T_SEQ + m) * 2048 + nn] = o;
    }
  }
}

__device__ __forceinline__ unsigned long long pack_hv(unsigned tag, float h) {
  return (unsigned long long)tag | ((unsigned long long)__float_as_uint(h) << 32);
}

__global__ void hinit_k(const float* __restrict__ h0, int layer,
                        unsigned long long* __restrict__ hcomm) {
  int i = blockIdx.x * blockDim.x + threadIdx.x;   // 0..2047
  int dir = i >> 10, par = (i >> 9) & 1, j = i & 511;
  unsigned long long v;
  if (par == 0) {
    float h = (j < 500) ? h0[(layer * 2 + dir) * 500 + j] : 0.0f;
    v = pack_hv(0u, h);
  } else {
    v = 0xFFFFFFFFull;   // sentinel tag, value 0
  }
  hcomm[(size_t)(dir * 2 + par) * HPAD + j] = v;
}

// Persistent recurrence kernel: 32 WGs x 1024 threads; WG = (dir = blockIdx>>4,
// wgd = blockIdx&15) owns units [wgd*32, wgd*32+32).
// Wave w owns k-slice [w*32, w*32+32); lane owns 2 rows (r = lane*2+s,
// gate = r>>5, unit = r&31) -> wreg[2][32] register-resident (waves_per_eu pinned).
__global__ __launch_bounds__(1024)
__attribute__((amdgpu_waves_per_eu(4, 4)))
void lstm_k(
    const float* __restrict__ whh_base,   // [2][2000][500]
    const float* __restrict__ gin,        // [2][4096][2048]
    const float* __restrict__ c0,         // [4][500]
    float* __restrict__ xout,             // [4096][1024]
    unsigned long long* __restrict__ hcomm, // [2][2][512]
    int layer) {
  __shared__ float part[16][128];
  __shared__ float hbuf[16][32];

  const int tid = threadIdx.x;
  const int dir = blockIdx.x >> 4;
  const int wgd = blockIdx.x & 15;              // unit block [wgd*32, wgd*32+32)
  const int w = tid >> 6;
  const int lane = tid & 63;

  // ---- load recurrent weights into registers (2 rows x 32 k per lane) ----
  float wreg[2][32];
  const float* Wd = whh_base + (size_t)dir * 2000 * 500;
#pragma unroll
  for (int s = 0; s < 2; s++) {
    int rloc = lane * 2 + s;                    // 0..127
    int gate = rloc >> 5, u = rloc & 31;
    int j = wgd * 32 + u;
    int row = gate * 500 + j;
#pragma unroll
    for (int i = 0; i < 32; i++) {
      int k = w * 32 + i;
      wreg[s][i] = (j < 500 && k < 500) ? Wd[(size_t)row * 500 + k] : 0.0f;
    }
  }

  // wave0 lanes<32: persistent cell state (one unit per lane)
  float c = 0.0f;
  const int jmine = wgd * 32 + (lane & 31);
  if (w == 0 && lane < 32 && jmine < 500) c = c0[(layer * 2 + dir) * 500 + jmine];

  unsigned long long* hcd = hcomm + (size_t)dir * 2 * HPAD;
  bool dead = false;

  for (int t = 0; t < T_SEQ; t++) {
    const int t_in = (dir == 0) ? t : (T_SEQ - 1 - t);

    // prefetch input-projection gates (latency hidden under poll)
    float gi0 = 0, gi1 = 0, gi2 = 0, gi3 = 0;
    if (w == 0 && lane < 32) {
      const float* gb = gin + ((size_t)dir * T_SEQ + t_in) * 2048;
      gi0 = gb[jmine];
      gi1 = gb[512 + jmine];
      gi2 = gb[1024 + jmine];
      gi3 = gb[1536 + jmine];
    }

    // ---- poll my wave's h k-slice (tag==t), device-scope (proven) ----
    unsigned long long v = 0;
    if (!dead) {
      const unsigned long long* hp =
          hcd + (size_t)(t & 1) * HPAD + w * 32 + (lane & 31);
      int guard = 0;
      for (;;) {
        v = __hip_atomic_load(hp, __ATOMIC_RELAXED, __HIP_MEMORY_SCOPE_AGENT);
        if (__all((int)((unsigned)v == (unsigned)t))) break;
        if (++guard > (1 << 22)) { dead = true; break; }   // bail, never hang
      }
    }
    float hval = __uint_as_float((unsigned)(v >> 32));

    // ---- broadcast h within the wave via LDS (8 ds_read_b128, not 32 shfl) ----
    if (lane < 32) hbuf[w][lane] = hval;       // same-wave RAW, ordered by lgkmcnt
    float a0 = 0, a1 = 0;
#pragma unroll
    for (int b = 0; b < 8; b++) {
      float4 hv = *reinterpret_cast<const float4*>(&hbuf[w][b * 4]);
      a0 = fmaf(wreg[0][b * 4 + 0], hv.x, a0);
      a1 = fmaf(wreg[1][b * 4 + 0], hv.x, a1);
      a0 = fmaf(wreg[0][b * 4 + 1], hv.y, a0);
      a1 = fmaf(wreg[1][b * 4 + 1], hv.y, a1);
      a0 = fmaf(wreg[0][b * 4 + 2], hv.z, a0);
      a1 = fmaf(wreg[1][b * 4 + 2], hv.z, a1);
      a0 = fmaf(wreg[0][b * 4 + 3], hv.w, a0);
      a1 = fmaf(wreg[1][b * 4 + 3], hv.w, a1);
    }
    {
      float2 pv; pv.x = a0; pv.y = a1;
      *reinterpret_cast<float2*>(&part[w][lane * 2]) = pv;  // row r = lane*2+s
    }
    __syncthreads();

    // ---- cross-wave reduce: 8 threads per row over 16 wave-partials ----
    {
      int rr = tid >> 3, q = tid & 7;           // rr 0..127
      float sum = part[q][rr] + part[q + 8][rr];
      sum += __shfl_xor(sum, 1, 8);
      sum += __shfl_xor(sum, 2, 8);
      sum += __shfl_xor(sum, 4, 8);
      if (q == 0) part[0][rr] = sum;
    }
    __syncthreads();

    // ---- wave0 lanes<32: gate nonlinearity, state update, publish h ----
    if (w == 0 && lane < 32) {
      float xi = 1.0f / (1.0f + expf(-(part[0][lane] + gi0)));
      float xf = 1.0f / (1.0f + expf(-(part[0][32 + lane] + gi1)));
      float xg = tanhf(part[0][64 + lane] + gi2);
      float xo = 1.0f / (1.0f + expf(-(part[0][96 + lane] + gi3)));
      c = xf * c + xi * xg;
      float h = xo * tanhf(c);
      if (jmine < 500)
        xout[(size_t)t_in * 1024 + (size_t)dir * HPAD + jmine] = h;
      unsigned long long sv = pack_hv((unsigned)(t + 1), h);
      __hip_atomic_store(hcd + (size_t)((t + 1) & 1) * HPAD + jmine, sv,
                         __ATOMIC_RELAXED, __HIP_MEMORY_SCOPE_AGENT);
    }
  }
}

// feats[t][tag] = sum_k x2[t][k]*w_out[tag][k_real] + b_out[tag]
__global__ __launch_bounds__(256) void feats_k(
    const float* __restrict__ x2, const float* __restrict__ w_out,
    const float* __restrict__ b_out, float* __restrict__ feats) {
  int tid = threadIdx.x;
  int tag = tid & 15, tl = tid >> 4;
  int t = blockIdx.x * 16 + tl;
  float acc = 0.0f;
  for (int k = 0; k < 1024; k++) {
    int jk = k & 511;
    if (jk < 500)
      acc = fmaf(x2[(size_t)t * 1024 + k], w_out[tag * 1000 + (k >> 9) * 500 + jk], acc);
  }
  feats[t * 16 + tag] = acc + b_out[tag];
}

__global__ __launch_bounds__(256) void viterbi_k(
    const float* __restrict__ feats, const float* __restrict__ trans,
    int* __restrict__ bptr, float* __restrict__ out) {
  __shared__ float sfin[NTAG];
  __shared__ int sbest;
  int tid = threadIdx.x;
  if (tid < 64) {
    int tag = tid & 15;
    float treg[16];
#pragma unroll
    for (int p = 0; p < 16; p++) treg[p] = trans[tag * 16 + p];
    float s = (tag == 14) ? 0.0f : -10000.0f;   // START=14
    for (int t = 0; t < T_SEQ; t++) {
      float best = -3.4e38f;
      int barg = 0;
#pragma unroll
      for (int p = 0; p < 16; p++) {
        float cand = __shfl(s, p, 16) + treg[p];
        if (cand > best) { best = cand; barg = p; }   // strict > : first-max (np.argmax)
      }
      s = best + feats[t * 16 + tag];
      if (tid < 16) bptr[t * 16 + tag] = barg;
    }
    s += trans[15 * 16 + tag];                   // STOP=15
    if (tid < 16) sfin[tag] = s;
  }
  __syncthreads();
  if (tid == 0) {
    float best = -3.4e38f;
    int bt = 0;
    for (int p = 0; p < 16; p++) {
      float vv = sfin[p];
      if (vv > best) { best = vv; bt = p; }
    }
    out[0] = best;
    sbest = bt;
  }
  __syncthreads();
  int bt = sbest;
  for (int i = tid; i < T_SEQ - 1; i += blockDim.x)
    out[1 + i] = (float)bptr[(i + 1) * 16 + bt];
  if (tid == 0) out[T_SEQ] = (float)bt;
}

extern "C" void kernel_launch(void* const* d_in, const int* in_sizes, int n_in,
                              void* d_out, int out_size, void* d_ws, size_t ws_size,
                              hipStream_t stream) {
  const int*   sent  = (const int*)d_in[0];
  const float* embed = (const float*)d_in[1];
  const float* wih0  = (const float*)d_in[2];
  const float* whh0  = (const float*)d_in[3];
  const float* bih0  = (const float*)d_in[4];
  const float* bhh0  = (const float*)d_in[5];
  const float* wih1  = (const float*)d_in[6];
  const float* whh1  = (const float*)d_in[7];
  const float* bih1  = (const float*)d_in[8];
  const float* bhh1  = (const float*)d_in[9];
  const float* w_out = (const float*)d_in[10];
  const float* b_out = (const float*)d_in[11];
  const float* trans = (const float*)d_in[12];
  const float* h0    = (const float*)d_in[13];
  const float* c0    = (const float*)d_in[14];
  float* out = (float*)d_out;

  char* ws = (char*)d_ws;
  float* x0    = (float*)(ws + 0);
  float* x1    = (float*)(ws + 8388608);
  float* x2    = (float*)(ws + 25165824);
  float* gin   = (float*)(ws + 41943040);
  float* feats = (float*)(ws + 109051904);
  int*   bptr  = (int*)(ws + 109314048);
  unsigned long long* hcomm = (unsigned long long*)(ws + 109576192);

  // zero x1+x2 (contiguous 32MB) so pad columns are 0
  zero_k<<<2048, 256, 0, stream>>>(x1, 2 * T_SEQ * 1024);
  embed_k<<<T_SEQ, 256, 0, stream>>>(sent, embed, x0);

  // layer 0
  gin_gemm_k<<<dim3(16, 32, 2), 256, 0, stream>>>(x0, 512, wih0, bih0, bhh0, 500, gin);
  hinit_k<<<2, 1024, 0, stream>>>(h0, 0, hcomm);
  lstm_k<<<32, 1024, 0, stream>>>(whh0, gin, c0, x1, hcomm, 0);

  // layer 1
  gin_gemm_k<<<dim3(16, 32, 2), 256, 0, stream>>>(x1, 1024, wih1, bih1, bhh1, 1000, gin);
  hinit_k<<<2, 1024, 0, stream>>>(h0, 1, hcomm);
  lstm_k<<<32, 1024, 0, stream>>>(whh1, gin, c0, x2, hcomm, 1);

  // output projection + viterbi
  feats_k<<<T_SEQ / 16, 256, 0, stream>>>(x2, w_out, b_out, feats);
  viterbi_k<<<1, 256, 0, stream>>>(feats, trans, bptr, out);
}

// Round 6
// 18649.406 us; speedup vs baseline: 2.7324x; 1.0272x over previous
//
#include <hip/hip_runtime.h>

// LSTM-CRF on MI355X.
// Pipeline: embed -> gemm(gin L0) -> lstm L0 -> gemm(gin L1) -> lstm L1 -> feats -> viterbi.
// Recurrence: 16 WGs per direction (32 units each), h exchanged per step via tagged u64
// {tag:u32, h:f32} mailbox with DEVICE-SCOPE relaxed atomics (proven semantics).
// Round-5 lesson (counters): even with waves_per_eu(4,4) granting 128 VGPRs, the compiler
// kept VGPR_Count=60 and REMATERIALIZED wreg from L1 every step (256KB/CU/step through the
// ~64B/cy L1 port ~ 4100 cy/step ~ 90% of lstm time). Fix: pin the loaded weights with
// asm volatile("" : "+v") -- values become opaque, rematerialization illegal, must stay
// in VGPRs (~124 live, fits the 128 budget).

#define T_SEQ 4096
#define HPAD  512
#define NTAG  16

// ---------------- workspace layout (bytes) ----------------
// x0   : [4096][512]  f32   8388608  @ 0
// x1   : [4096][1024] f32  16777216  @ 8388608
// x2   : [4096][1024] f32  16777216  @ 25165824
// gin  : [2][4096][2048] f32 67108864 @ 41943040
// feats: [4096][16] f32     262144  @ 109051904
// bptr : [4096][16] i32     262144  @ 109314048
// hcomm: [2][2][512] u64     16384  @ 109576192

__global__ void zero_k(float* __restrict__ p, int n) {
  int i = blockIdx.x * blockDim.x + threadIdx.x;
  int stride = gridDim.x * blockDim.x;
  for (; i < n; i += stride) p[i] = 0.0f;
}

__global__ void embed_k(const int* __restrict__ sent, const float* __restrict__ ew,
                        float* __restrict__ x0) {
  int t = blockIdx.x;
  int row = sent[t];
  for (int k = threadIdx.x; k < HPAD; k += blockDim.x)
    x0[(size_t)t * HPAD + k] = (k < 500) ? ew[(size_t)row * 500 + k] : 0.0f;
}

// G[dir][t][n] = sum_k A[t][k] * Wmap[dir][n][k] + bias[n]  (f32, 128x128 tile, 8x8/thread)
__global__ __launch_bounds__(256) void gin_gemm_k(
    const float* __restrict__ A, int KA,
    const float* __restrict__ wih, const float* __restrict__ bih,
    const float* __restrict__ bhh, int Kreal, float* __restrict__ G) {
  const int dir = blockIdx.z;
  const int bm = blockIdx.y, bn = blockIdx.x;
  const float* W = wih + (size_t)dir * 2000 * Kreal;

  __shared__ float As[16][128];
  __shared__ float Bs[16][128];

  const int tid = threadIdx.x;
  const int tx = tid & 15, ty = tid >> 4;
  float acc[8][8] = {};

  for (int k0 = 0; k0 < KA; k0 += 16) {
#pragma unroll
    for (int q = 0; q < 2; q++) {
      int f4 = tid + q * 256;              // 0..511
      int m = f4 >> 2, kc = (f4 & 3) * 4;
      float4 av = *reinterpret_cast<const float4*>(A + (size_t)(bm * 128 + m) * KA + k0 + kc);
      As[kc + 0][m] = av.x; As[kc + 1][m] = av.y;
      As[kc + 2][m] = av.z; As[kc + 3][m] = av.w;
    }
#pragma unroll
    for (int q = 0; q < 2; q++) {
      int f4 = tid + q * 256;
      int n = f4 >> 2, kc = (f4 & 3) * 4;
      int nn = bn * 128 + n;
      int gate = nn >> 9, j = nn & 511;
#pragma unroll
      for (int e = 0; e < 4; e++) {
        int k = k0 + kc + e;
        int jk = k & 511, half = k >> 9;
        float v = 0.0f;
        if (j < 500 && jk < 500)
          v = W[(size_t)(gate * 500 + j) * Kreal + half * 500 + jk];
        Bs[kc + e][n] = v;
      }
    }
    __syncthreads();
#pragma unroll
    for (int kk = 0; kk < 16; kk++) {
      float a[8], b[8];
      *reinterpret_cast<float4*>(&a[0]) = *reinterpret_cast<const float4*>(&As[kk][ty * 8]);
      *reinterpret_cast<float4*>(&a[4]) = *reinterpret_cast<const float4*>(&As[kk][ty * 8 + 4]);
      *reinterpret_cast<float4*>(&b[0]) = *reinterpret_cast<const float4*>(&Bs[kk][tx * 8]);
      *reinterpret_cast<float4*>(&b[4]) = *reinterpret_cast<const float4*>(&Bs[kk][tx * 8 + 4]);
#pragma unroll
      for (int i = 0; i < 8; i++)
#pragma unroll
        for (int j = 0; j < 8; j++) acc[i][j] = fmaf(a[i], b[j], acc[i][j]);
    }
    __syncthreads();
  }
#pragma unroll
  for (int i = 0; i < 8; i++) {
#pragma unroll
    for (int j = 0; j < 8; j++) {
      int m = bm * 128 + ty * 8 + i;
      int nn = bn * 128 + tx * 8 + j;
      int gate = nn >> 9, ju = nn & 511;
      float o = 0.0f;
      if (ju < 500) {
        int r = gate * 500 + ju;
        o = acc[i][j] + bih[dir * 2000 + r] + bhh[dir * 2000 + r];
      }
      G[((size_t)dir * T_SEQ + m) * 2048 + nn] = o;
    }
  }
}

__device__ __forceinline__ unsigned long long pack_hv(unsigned tag, float h) {
  return (unsigned long long)tag | ((unsigned long long)__float_as_uint(h) << 32);
}

__global__ void hinit_k(const float* __restrict__ h0, int layer,
                        unsigned long long* __restrict__ hcomm) {
  int i = blockIdx.x * blockDim.x + threadIdx.x;   // 0..2047
  int dir = i >> 10, par = (i >> 9) & 1, j = i & 511;
  unsigned long long v;
  if (par == 0) {
    float h = (j < 500) ? h0[(layer * 2 + dir) * 500 + j] : 0.0f;
    v = pack_hv(0u, h);
  } else {
    v = 0xFFFFFFFFull;   // sentinel tag, value 0
  }
  hcomm[(size_t)(dir * 2 + par) * HPAD + j] = v;
}

// Persistent recurrence kernel: 32 WGs x 1024 threads; WG = (dir = blockIdx>>4,
// wgd = blockIdx&15) owns units [wgd*32, wgd*32+32).
// Wave w owns k-slice [w*32, w*32+32); lane owns 2 rows (r = lane*2+s,
// gate = r>>5, unit = r&31) -> wreg[2][32] pinned register-resident via asm touch.
__global__ __launch_bounds__(1024)
__attribute__((amdgpu_waves_per_eu(4, 4)))
void lstm_k(
    const float* __restrict__ whh_base,   // [2][2000][500]
    const float* __restrict__ gin,        // [2][4096][2048]
    const float* __restrict__ c0,         // [4][500]
    float* __restrict__ xout,             // [4096][1024]
    unsigned long long* __restrict__ hcomm, // [2][2][512]
    int layer) {
  __shared__ float part[16][128];
  __shared__ float hbuf[16][32];

  const int tid = threadIdx.x;
  const int dir = blockIdx.x >> 4;
  const int wgd = blockIdx.x & 15;              // unit block [wgd*32, wgd*32+32)
  const int w = tid >> 6;
  const int lane = tid & 63;

  // ---- load recurrent weights into registers (2 rows x 32 k per lane) ----
  float wreg[2][32];
  const float* Wd = whh_base + (size_t)dir * 2000 * 500;
#pragma unroll
  for (int s = 0; s < 2; s++) {
    int rloc = lane * 2 + s;                    // 0..127
    int gate = rloc >> 5, u = rloc & 31;
    int j = wgd * 32 + u;
    int row = gate * 500 + j;
#pragma unroll
    for (int i = 0; i < 32; i++) {
      int k = w * 32 + i;
      wreg[s][i] = (j < 500 && k < 500) ? Wd[(size_t)row * 500 + k] : 0.0f;
    }
  }
  // Pin: values become opaque -> compiler cannot rematerialize from memory each step,
  // must keep all 64 in VGPRs for the whole kernel (fits the 128-VGPR/wave budget).
#pragma unroll
  for (int s = 0; s < 2; s++)
#pragma unroll
    for (int i = 0; i < 32; i++)
      asm volatile("" : "+v"(wreg[s][i]));

  // wave0 lanes<32: persistent cell state (one unit per lane)
  float c = 0.0f;
  const int jmine = wgd * 32 + (lane & 31);
  if (w == 0 && lane < 32 && jmine < 500) c = c0[(layer * 2 + dir) * 500 + jmine];

  unsigned long long* hcd = hcomm + (size_t)dir * 2 * HPAD;
  bool dead = false;

  for (int t = 0; t < T_SEQ; t++) {
    const int t_in = (dir == 0) ? t : (T_SEQ - 1 - t);

    // prefetch input-projection gates (latency hidden under poll)
    float gi0 = 0, gi1 = 0, gi2 = 0, gi3 = 0;
    if (w == 0 && lane < 32) {
      const float* gb = gin + ((size_t)dir * T_SEQ + t_in) * 2048;
      gi0 = gb[jmine];
      gi1 = gb[512 + jmine];
      gi2 = gb[1024 + jmine];
      gi3 = gb[1536 + jmine];
    }

    // ---- poll my wave's h k-slice (tag==t), device-scope (proven) ----
    unsigned long long v = 0;
    if (!dead) {
      const unsigned long long* hp =
          hcd + (size_t)(t & 1) * HPAD + w * 32 + (lane & 31);
      int guard = 0;
      for (;;) {
        v = __hip_atomic_load(hp, __ATOMIC_RELAXED, __HIP_MEMORY_SCOPE_AGENT);
        if (__all((int)((unsigned)v == (unsigned)t))) break;
        if (++guard > (1 << 22)) { dead = true; break; }   // bail, never hang
      }
    }
    float hval = __uint_as_float((unsigned)(v >> 32));

    // ---- broadcast h within the wave via LDS (8 ds_read_b128) ----
    if (lane < 32) hbuf[w][lane] = hval;       // same-wave RAW, ordered by lgkmcnt
    float a0 = 0, a1 = 0;
#pragma unroll
    for (int b = 0; b < 8; b++) {
      float4 hv = *reinterpret_cast<const float4*>(&hbuf[w][b * 4]);
      a0 = fmaf(wreg[0][b * 4 + 0], hv.x, a0);
      a1 = fmaf(wreg[1][b * 4 + 0], hv.x, a1);
      a0 = fmaf(wreg[0][b * 4 + 1], hv.y, a0);
      a1 = fmaf(wreg[1][b * 4 + 1], hv.y, a1);
      a0 = fmaf(wreg[0][b * 4 + 2], hv.z, a0);
      a1 = fmaf(wreg[1][b * 4 + 2], hv.z, a1);
      a0 = fmaf(wreg[0][b * 4 + 3], hv.w, a0);
      a1 = fmaf(wreg[1][b * 4 + 3], hv.w, a1);
    }
    {
      float2 pv; pv.x = a0; pv.y = a1;
      *reinterpret_cast<float2*>(&part[w][lane * 2]) = pv;  // row r = lane*2+s
    }
    __syncthreads();

    // ---- cross-wave reduce: 8 threads per row over 16 wave-partials ----
    {
      int rr = tid >> 3, q = tid & 7;           // rr 0..127
      float sum = part[q][rr] + part[q + 8][rr];
      sum += __shfl_xor(sum, 1, 8);
      sum += __shfl_xor(sum, 2, 8);
      sum += __shfl_xor(sum, 4, 8);
      if (q == 0) part[0][rr] = sum;
    }
    __syncthreads();

    // ---- wave0 lanes<32: gate nonlinearity, state update, publish h ----
    if (w == 0 && lane < 32) {
      float xi = 1.0f / (1.0f + expf(-(part[0][lane] + gi0)));
      float xf = 1.0f / (1.0f + expf(-(part[0][32 + lane] + gi1)));
      float xg = tanhf(part[0][64 + lane] + gi2);
      float xo = 1.0f / (1.0f + expf(-(part[0][96 + lane] + gi3)));
      c = xf * c + xi * xg;
      float h = xo * tanhf(c);
      if (jmine < 500)
        xout[(size_t)t_in * 1024 + (size_t)dir * HPAD + jmine] = h;
      unsigned long long sv = pack_hv((unsigned)(t + 1), h);
      __hip_atomic_store(hcd + (size_t)((t + 1) & 1) * HPAD + jmine, sv,
                         __ATOMIC_RELAXED, __HIP_MEMORY_SCOPE_AGENT);
    }
  }
}

// feats[t][tag] = sum_k x2[t][k]*w_out[tag][k_real] + b_out[tag]
__global__ __launch_bounds__(256) void feats_k(
    const float* __restrict__ x2, const float* __restrict__ w_out,
    const float* __restrict__ b_out, float* __restrict__ feats) {
  int tid = threadIdx.x;
  int tag = tid & 15, tl = tid >> 4;
  int t = blockIdx.x * 16 + tl;
  float acc = 0.0f;
  for (int k = 0; k < 1024; k++) {
    int jk = k & 511;
    if (jk < 500)
      acc = fmaf(x2[(size_t)t * 1024 + k], w_out[tag * 1000 + (k >> 9) * 500 + jk], acc);
  }
  feats[t * 16 + tag] = acc + b_out[tag];
}

__global__ __launch_bounds__(256) void viterbi_k(
    const float* __restrict__ feats, const float* __restrict__ trans,
    int* __restrict__ bptr, float* __restrict__ out) {
  __shared__ float sfin[NTAG];
  __shared__ int sbest;
  int tid = threadIdx.x;
  if (tid < 64) {
    int tag = tid & 15;
    float treg[16];
#pragma unroll
    for (int p = 0; p < 16; p++) treg[p] = trans[tag * 16 + p];
    float s = (tag == 14) ? 0.0f : -10000.0f;   // START=14
    for (int t = 0; t < T_SEQ; t++) {
      float best = -3.4e38f;
      int barg = 0;
#pragma unroll
      for (int p = 0; p < 16; p++) {
        float cand = __shfl(s, p, 16) + treg[p];
        if (cand > best) { best = cand; barg = p; }   // strict > : first-max (np.argmax)
      }
      s = best + feats[t * 16 + tag];
      if (tid < 16) bptr[t * 16 + tag] = barg;
    }
    s += trans[15 * 16 + tag];                   // STOP=15
    if (tid < 16) sfin[tag] = s;
  }
  __syncthreads();
  if (tid == 0) {
    float best = -3.4e38f;
    int bt = 0;
    for (int p = 0; p < 16; p++) {
      float vv = sfin[p];
      if (vv > best) { best = vv; bt = p; }
    }
    out[0] = best;
    sbest = bt;
  }
  __syncthreads();
  int bt = sbest;
  for (int i = tid; i < T_SEQ - 1; i += blockDim.x)
    out[1 + i] = (float)bptr[(i + 1) * 16 + bt];
  if (tid == 0) out[T_SEQ] = (float)bt;
}

extern "C" void kernel_launch(void* const* d_in, const int* in_sizes, int n_in,
                              void* d_out, int out_size, void* d_ws, size_t ws_size,
                              hipStream_t stream) {
  const int*   sent  = (const int*)d_in[0];
  const float* embed = (const float*)d_in[1];
  const float* wih0  = (const float*)d_in[2];
  const float* whh0  = (const float*)d_in[3];
  const float* bih0  = (const float*)d_in[4];
  const float* bhh0  = (const float*)d_in[5];
  const float* wih1  = (const float*)d_in[6];
  const float* whh1  = (const float*)d_in[7];
  const float* bih1  = (const float*)d_in[8];
  const float* bhh1  = (const float*)d_in[9];
  const float* w_out = (const float*)d_in[10];
  const float* b_out = (const float*)d_in[11];
  const float* trans = (const float*)d_in[12];
  const float* h0    = (const float*)d_in[13];
  const float* c0    = (const float*)d_in[14];
  float* out = (float*)d_out;

  char* ws = (char*)d_ws;
  float* x0    = (float*)(ws + 0);
  float* x1    = (float*)(ws + 8388608);
  float* x2    = (float*)(ws + 25165824);
  float* gin   = (float*)(ws + 41943040);
  float* feats = (float*)(ws + 109051904);
  int*   bptr  = (int*)(ws + 109314048);
  unsigned long long* hcomm = (unsigned long long*)(ws + 109576192);

  // zero x1+x2 (contiguous 32MB) so pad columns are 0
  zero_k<<<2048, 256, 0, stream>>>(x1, 2 * T_SEQ * 1024);
  embed_k<<<T_SEQ, 256, 0, stream>>>(sent, embed, x0);

  // layer 0
  gin_gemm_k<<<dim3(16, 32, 2), 256, 0, stream>>>(x0, 512, wih0, bih0, bhh0, 500, gin);
  hinit_k<<<2, 1024, 0, stream>>>(h0, 0, hcomm);
  lstm_k<<<32, 1024, 0, stream>>>(whh0, gin, c0, x1, hcomm, 0);

  // layer 1
  gin_gemm_k<<<dim3(16, 32, 2), 256, 0, stream>>>(x1, 1024, wih1, bih1, bhh1, 1000, gin);
  hinit_k<<<2, 1024, 0, stream>>>(h0, 1, hcomm);
  lstm_k<<<32, 1024, 0, stream>>>(whh1, gin, c0, x2, hcomm, 1);

  // output projection + viterbi
  feats_k<<<T_SEQ / 16, 256, 0, stream>>>(x2, w_out, b_out, feats);
  viterbi_k<<<1, 256, 0, stream>>>(feats, trans, bptr, out);
}

// Round 7
// 15243.617 us; speedup vs baseline: 3.3429x; 1.2234x over previous
//
#include <hip/hip_runtime.h>

// LSTM-CRF on MI355X.
// Pipeline: embed -> gemm(gin L0) -> lstm L0 -> gemm(gin L1) -> lstm L1 -> feats -> viterbi.
// Recurrence: 32 WGs per direction (16 units each), h exchanged per step via tagged u64
// {tag:u32, h:f32} mailbox with DEVICE-SCOPE relaxed atomics (proven semantics).
// Round-6 lesson: weight-remat theory dead (asm pin = null result). Counters say the
// per-step cost is a serial latency chain: poll ~1200cy, DS pipe ~1500cy, 2 barriers +
// 16-wave straggle ~800cy, conflicts 450cy. This round halves the chain: one row per
// lane (32 weights), part write = 1 b32, NO cross-wave tree reduce, ONE barrier/step
// (wave0 linearly sums 16 partials per row post-barrier; next-step part writes can't
// race it because they require h(t+1), which wave0 publishes only after reading).

#define T_SEQ 4096
#define HPAD  512
#define NTAG  16

// ---------------- workspace layout (bytes) ----------------
// x0   : [4096][512]  f32   8388608  @ 0
// x1   : [4096][1024] f32  16777216  @ 8388608
// x2   : [4096][1024] f32  16777216  @ 25165824
// gin  : [2][4096][2048] f32 67108864 @ 41943040
// feats: [4096][16] f32     262144  @ 109051904
// bptr : [4096][16] i32     262144  @ 109314048
// hcomm: [2][2][512] u64     16384  @ 109576192

__global__ void zero_k(float* __restrict__ p, int n) {
  int i = blockIdx.x * blockDim.x + threadIdx.x;
  int stride = gridDim.x * blockDim.x;
  for (; i < n; i += stride) p[i] = 0.0f;
}

__global__ void embed_k(const int* __restrict__ sent, const float* __restrict__ ew,
                        float* __restrict__ x0) {
  int t = blockIdx.x;
  int row = sent[t];
  for (int k = threadIdx.x; k < HPAD; k += blockDim.x)
    x0[(size_t)t * HPAD + k] = (k < 500) ? ew[(size_t)row * 500 + k] : 0.0f;
}

// G[dir][t][n] = sum_k A[t][k] * Wmap[dir][n][k] + bias[n]  (f32, 128x128 tile, 8x8/thread)
__global__ __launch_bounds__(256) void gin_gemm_k(
    const float* __restrict__ A, int KA,
    const float* __restrict__ wih, const float* __restrict__ bih,
    const float* __restrict__ bhh, int Kreal, float* __restrict__ G) {
  const int dir = blockIdx.z;
  const int bm = blockIdx.y, bn = blockIdx.x;
  const float* W = wih + (size_t)dir * 2000 * Kreal;

  __shared__ float As[16][128];
  __shared__ float Bs[16][128];

  const int tid = threadIdx.x;
  const int tx = tid & 15, ty = tid >> 4;
  float acc[8][8] = {};

  for (int k0 = 0; k0 < KA; k0 += 16) {
#pragma unroll
    for (int q = 0; q < 2; q++) {
      int f4 = tid + q * 256;              // 0..511
      int m = f4 >> 2, kc = (f4 & 3) * 4;
      float4 av = *reinterpret_cast<const float4*>(A + (size_t)(bm * 128 + m) * KA + k0 + kc);
      As[kc + 0][m] = av.x; As[kc + 1][m] = av.y;
      As[kc + 2][m] = av.z; As[kc + 3][m] = av.w;
    }
#pragma unroll
    for (int q = 0; q < 2; q++) {
      int f4 = tid + q * 256;
      int n = f4 >> 2, kc = (f4 & 3) * 4;
      int nn = bn * 128 + n;
      int gate = nn >> 9, j = nn & 511;
#pragma unroll
      for (int e = 0; e < 4; e++) {
        int k = k0 + kc + e;
        int jk = k & 511, half = k >> 9;
        float v = 0.0f;
        if (j < 500 && jk < 500)
          v = W[(size_t)(gate * 500 + j) * Kreal + half * 500 + jk];
        Bs[kc + e][n] = v;
      }
    }
    __syncthreads();
#pragma unroll
    for (int kk = 0; kk < 16; kk++) {
      float a[8], b[8];
      *reinterpret_cast<float4*>(&a[0]) = *reinterpret_cast<const float4*>(&As[kk][ty * 8]);
      *reinterpret_cast<float4*>(&a[4]) = *reinterpret_cast<const float4*>(&As[kk][ty * 8 + 4]);
      *reinterpret_cast<float4*>(&b[0]) = *reinterpret_cast<const float4*>(&Bs[kk][tx * 8]);
      *reinterpret_cast<float4*>(&b[4]) = *reinterpret_cast<const float4*>(&Bs[kk][tx * 8 + 4]);
#pragma unroll
      for (int i = 0; i < 8; i++)
#pragma unroll
        for (int j = 0; j < 8; j++) acc[i][j] = fmaf(a[i], b[j], acc[i][j]);
    }
    __syncthreads();
  }
#pragma unroll
  for (int i = 0; i < 8; i++) {
#pragma unroll
    for (int j = 0; j < 8; j++) {
      int m = bm * 128 + ty * 8 + i;
      int nn = bn * 128 + tx * 8 + j;
      int gate = nn >> 9, ju = nn & 511;
      float o = 0.0f;
      if (ju < 500) {
        int r = gate * 500 + ju;
        o = acc[i][j] + bih[dir * 2000 + r] + bhh[dir * 2000 + r];
      }
      G[((size_t)dir * T_SEQ + m) * 2048 + nn] = o;
    }
  }
}

__device__ __forceinline__ unsigned long long pack_hv(unsigned tag, float h) {
  return (unsigned long long)tag | ((unsigned long long)__float_as_uint(h) << 32);
}

__global__ void hinit_k(const float* __restrict__ h0, int layer,
                        unsigned long long* __restrict__ hcomm) {
  int i = blockIdx.x * blockDim.x + threadIdx.x;   // 0..2047
  int dir = i >> 10, par = (i >> 9) & 1, j = i & 511;
  unsigned long long v;
  if (par == 0) {
    float h = (j < 500) ? h0[(layer * 2 + dir) * 500 + j] : 0.0f;
    v = pack_hv(0u, h);
  } else {
    v = 0xFFFFFFFFull;   // sentinel tag, value 0
  }
  hcomm[(size_t)(dir * 2 + par) * HPAD + j] = v;
}

// Persistent recurrence kernel: 64 WGs x 1024 threads; WG = (dir = blockIdx>>5,
// wgd = blockIdx&31) owns units [wgd*16, wgd*16+16)  (64 rows = 4 gates x 16 units).
// Wave w owns k-slice [w*32, w*32+32); lane owns ONE row (gate=lane>>4, unit=lane&15)
// -> wreg[32]/lane. One barrier per step; wave0 sums 16 partials/row and publishes.
__global__ __launch_bounds__(1024)
__attribute__((amdgpu_waves_per_eu(4, 4)))
void lstm_k(
    const float* __restrict__ whh_base,   // [2][2000][500]
    const float* __restrict__ gin,        // [2][4096][2048]
    const float* __restrict__ c0,         // [4][500]
    float* __restrict__ xout,             // [4096][1024]
    unsigned long long* __restrict__ hcomm, // [2][2][512]
    int layer) {
  __shared__ float part[16][68];          // pad 68: 2-way max on all access patterns
  __shared__ float hbuf[16][32];

  const int tid = threadIdx.x;
  const int dir = blockIdx.x >> 5;
  const int wgd = blockIdx.x & 31;        // unit block [wgd*16, wgd*16+16)
  const int w = tid >> 6;
  const int lane = tid & 63;

  const int gate = lane >> 4;             // my row's gate (0=i,1=f,2=g,3=o)
  const int ul   = lane & 15;             // my row's local unit
  const int j    = wgd * 16 + ul;         // global unit (0..511)
  const int row  = gate * 500 + j;

  // ---- load recurrent weights into registers (1 row x 32 k per lane) ----
  float wreg[32];
  const float* Wd = whh_base + (size_t)dir * 2000 * 500;
#pragma unroll
  for (int i = 0; i < 32; i++) {
    int k = w * 32 + i;
    wreg[i] = (j < 500 && k < 500) ? Wd[(size_t)row * 500 + k] : 0.0f;
  }
#pragma unroll
  for (int i = 0; i < 32; i++) asm volatile("" : "+v"(wreg[i]));

  // wave0 lanes<16: persistent cell state (one unit per lane)
  float c = 0.0f;
  if (w == 0 && lane < 16 && j < 500) c = c0[(layer * 2 + dir) * 500 + j];

  unsigned long long* hcd = hcomm + (size_t)dir * 2 * HPAD;
  bool dead = false;

  for (int t = 0; t < T_SEQ; t++) {
    const int t_in = (dir == 0) ? t : (T_SEQ - 1 - t);

    // prefetch input-projection gate value for my row (latency hidden under poll)
    float gi = 0.0f;
    if (w == 0) {
      const float* gb = gin + ((size_t)dir * T_SEQ + t_in) * 2048;
      gi = gb[gate * 512 + j];
    }

    // ---- poll my wave's h k-slice (tag==t), device-scope (proven) ----
    unsigned long long v = 0;
    if (!dead) {
      const unsigned long long* hp =
          hcd + (size_t)(t & 1) * HPAD + w * 32 + (lane & 31);
      int guard = 0;
      for (;;) {
        v = __hip_atomic_load(hp, __ATOMIC_RELAXED, __HIP_MEMORY_SCOPE_AGENT);
        if (__all((int)((unsigned)v == (unsigned)t))) break;
        if (++guard > (1 << 22)) { dead = true; break; }   // bail, never hang
      }
    }
    float hval = __uint_as_float((unsigned)(v >> 32));

    // ---- broadcast h within the wave via LDS, matvec partial for my row ----
    if (lane < 32) hbuf[w][lane] = hval;   // same-wave RAW, ordered by lgkmcnt
    float a = 0.0f;
#pragma unroll
    for (int b = 0; b < 8; b++) {
      float4 hv = *reinterpret_cast<const float4*>(&hbuf[w][b * 4]);
      a = fmaf(wreg[b * 4 + 0], hv.x, a);
      a = fmaf(wreg[b * 4 + 1], hv.y, a);
      a = fmaf(wreg[b * 4 + 2], hv.z, a);
      a = fmaf(wreg[b * 4 + 3], hv.w, a);
    }
    part[w][lane] = a;
    __syncthreads();   // the ONLY barrier per step

    // ---- wave0: per-row linear sum of 16 partials, gates, publish ----
    // Race-free vs next step: waves can only overwrite part(t+1) after polling
    // h(t+1), which requires the publish below -- which follows these reads.
    if (w == 0) {
      float s = gi;
#pragma unroll
      for (int q = 0; q < 16; q++) s += part[q][lane];
      float nl = (gate == 2) ? tanhf(s) : (1.0f / (1.0f + expf(-s)));
      float xf = __shfl(nl, lane + 16, 64);
      float xg = __shfl(nl, lane + 32, 64);
      float xo = __shfl(nl, lane + 48, 64);
      if (lane < 16) {
        c = xf * c + nl * xg;              // nl here is xi (gate 0)
        float h = xo * tanhf(c);
        unsigned long long sv = pack_hv((unsigned)(t + 1), h);
        __hip_atomic_store(hcd + (size_t)((t + 1) & 1) * HPAD + j, sv,
                           __ATOMIC_RELAXED, __HIP_MEMORY_SCOPE_AGENT);
        if (j < 500)
          xout[(size_t)t_in * 1024 + (size_t)dir * HPAD + j] = h;
      }
    }
  }
}

// feats[t][tag] = sum_k x2[t][k]*w_out[tag][k_real] + b_out[tag]
__global__ __launch_bounds__(256) void feats_k(
    const float* __restrict__ x2, const float* __restrict__ w_out,
    const float* __restrict__ b_out, float* __restrict__ feats) {
  int tid = threadIdx.x;
  int tag = tid & 15, tl = tid >> 4;
  int t = blockIdx.x * 16 + tl;
  float acc = 0.0f;
  for (int k = 0; k < 1024; k++) {
    int jk = k & 511;
    if (jk < 500)
      acc = fmaf(x2[(size_t)t * 1024 + k], w_out[tag * 1000 + (k >> 9) * 500 + jk], acc);
  }
  feats[t * 16 + tag] = acc + b_out[tag];
}

__global__ __launch_bounds__(256) void viterbi_k(
    const float* __restrict__ feats, const float* __restrict__ trans,
    int* __restrict__ bptr, float* __restrict__ out) {
  __shared__ float sfin[NTAG];
  __shared__ int sbest;
  int tid = threadIdx.x;
  if (tid < 64) {
    int tag = tid & 15;
    float treg[16];
#pragma unroll
    for (int p = 0; p < 16; p++) treg[p] = trans[tag * 16 + p];
    float s = (tag == 14) ? 0.0f : -10000.0f;   // START=14
    for (int t = 0; t < T_SEQ; t++) {
      float best = -3.4e38f;
      int barg = 0;
#pragma unroll
      for (int p = 0; p < 16; p++) {
        float cand = __shfl(s, p, 16) + treg[p];
        if (cand > best) { best = cand; barg = p; }   // strict > : first-max (np.argmax)
      }
      s = best + feats[t * 16 + tag];
      if (tid < 16) bptr[t * 16 + tag] = barg;
    }
    s += trans[15 * 16 + tag];                   // STOP=15
    if (tid < 16) sfin[tag] = s;
  }
  __syncthreads();
  if (tid == 0) {
    float best = -3.4e38f;
    int bt = 0;
    for (int p = 0; p < 16; p++) {
      float vv = sfin[p];
      if (vv > best) { best = vv; bt = p; }
    }
    out[0] = best;
    sbest = bt;
  }
  __syncthreads();
  int bt = sbest;
  for (int i = tid; i < T_SEQ - 1; i += blockDim.x)
    out[1 + i] = (float)bptr[(i + 1) * 16 + bt];
  if (tid == 0) out[T_SEQ] = (float)bt;
}

extern "C" void kernel_launch(void* const* d_in, const int* in_sizes, int n_in,
                              void* d_out, int out_size, void* d_ws, size_t ws_size,
                              hipStream_t stream) {
  const int*   sent  = (const int*)d_in[0];
  const float* embed = (const float*)d_in[1];
  const float* wih0  = (const float*)d_in[2];
  const float* whh0  = (const float*)d_in[3];
  const float* bih0  = (const float*)d_in[4];
  const float* bhh0  = (const float*)d_in[5];
  const float* wih1  = (const float*)d_in[6];
  const float* whh1  = (const float*)d_in[7];
  const float* bih1  = (const float*)d_in[8];
  const float* bhh1  = (const float*)d_in[9];
  const float* w_out = (const float*)d_in[10];
  const float* b_out = (const float*)d_in[11];
  const float* trans = (const float*)d_in[12];
  const float* h0    = (const float*)d_in[13];
  const float* c0    = (const float*)d_in[14];
  float* out = (float*)d_out;

  char* ws = (char*)d_ws;
  float* x0    = (float*)(ws + 0);
  float* x1    = (float*)(ws + 8388608);
  float* x2    = (float*)(ws + 25165824);
  float* gin   = (float*)(ws + 41943040);
  float* feats = (float*)(ws + 109051904);
  int*   bptr  = (int*)(ws + 109314048);
  unsigned long long* hcomm = (unsigned long long*)(ws + 109576192);

  // zero x1+x2 (contiguous 32MB) so pad columns are 0
  zero_k<<<2048, 256, 0, stream>>>(x1, 2 * T_SEQ * 1024);
  embed_k<<<T_SEQ, 256, 0, stream>>>(sent, embed, x0);

  // layer 0
  gin_gemm_k<<<dim3(16, 32, 2), 256, 0, stream>>>(x0, 512, wih0, bih0, bhh0, 500, gin);
  hinit_k<<<2, 1024, 0, stream>>>(h0, 0, hcomm);
  lstm_k<<<64, 1024, 0, stream>>>(whh0, gin, c0, x1, hcomm, 0);

  // layer 1
  gin_gemm_k<<<dim3(16, 32, 2), 256, 0, stream>>>(x1, 1024, wih1, bih1, bhh1, 1000, gin);
  hinit_k<<<2, 1024, 0, stream>>>(h0, 1, hcomm);
  lstm_k<<<64, 1024, 0, stream>>>(whh1, gin, c0, x2, hcomm, 1);

  // output projection + viterbi
  feats_k<<<T_SEQ / 16, 256, 0, stream>>>(x2, w_out, b_out, feats);
  viterbi_k<<<1, 256, 0, stream>>>(feats, trans, bptr, out);
}